// Round 3
// baseline (757.732 us; speedup 1.0000x reference)
//
#include <hip/hip_runtime.h>
#include <cstdint>
#include <cmath>

typedef __attribute__((ext_vector_type(8))) short short8;
typedef __attribute__((ext_vector_type(4))) float floatx4;

#define DEV static __device__ __forceinline__

DEV float bf2f(uint16_t u) {
    union { uint32_t i; float f; } v; v.i = ((uint32_t)u) << 16; return v.f;
}
DEV uint16_t f2bf(float f) {
    union { float f; uint32_t i; } v; v.f = f;
    uint32_t r = (v.i + 0x7FFFu + ((v.i >> 16) & 1u)) >> 16;
    return (uint16_t)r;
}
DEV float swishf(float x) { return x / (1.f + __expf(-x)); }
DEV float geluf(float x) {
    const float c = 0.7978845608028654f;
    float t = tanhf(c * (x + 0.044715f * x * x * x));
    return 0.5f * x * (1.f + t);
}

DEV void gl_lds16(const uint16_t* g, uint16_t* l) {
    __builtin_amdgcn_global_load_lds(
        (const __attribute__((address_space(1))) uint32_t*)g,
        (__attribute__((address_space(3))) uint32_t*)l, 16, 0, 0);
}

// W packing: per 32-K chunk, layout [n(256)][36] (32 K-elems + 4 pad) = 9216 elems.
// Padded row (72 B) spreads the 16 l16-lanes of a b128 read across distinct banks.
#define CHUNK_E 9216
#define MAT_E   73728   // 8 chunks

// ---------------- convert fp32 -> bf16 (flat) ----------------
__global__ __launch_bounds__(256) void cvt_k(const float* __restrict__ src,
                                             uint16_t* __restrict__ dst, int n4) {
    int i = blockIdx.x * 256 + threadIdx.x;
    if (i >= n4) return;
    float4 f = ((const float4*)src)[i];
    uint16_t tmp[4] = { f2bf(f.x), f2bf(f.y), f2bf(f.z), f2bf(f.w) };
    ((uint2*)dst)[i] = *(uint2*)tmp;
}

// ---- transpose+convert: W[K,N=256] fp32 -> padded packed chunks ----
struct TArg { const float* src[15]; };

__global__ __launch_bounds__(256) void tpose_k(TArg ta, uint16_t* __restrict__ arena) {
    int z = blockIdx.z;
    const float* src; uint16_t* dst;
    if (z == 0) {
        if (blockIdx.y) return;
        src = ta.src[0]; dst = arena;                            // w_enc [32,256]
    } else if (z <= 39) {
        int q = z - 1; int ti = q / 3, s = q % 3;
        src = ta.src[1 + ti] + (size_t)s * 65536;
        dst = arena + CHUNK_E + (size_t)(ti * 3 + s) * MAT_E;
    } else {
        src = ta.src[14]; dst = arena + CHUNK_E + (size_t)39 * MAT_E;   // hw1
    }
    int k0 = blockIdx.y << 5;   // K chunk (32)
    int n0 = blockIdx.x << 6;   // N tile (64)
    __shared__ __align__(16) uint16_t tile[32][72];
    int t = threadIdx.x;
    {
        int r = t >> 3, c = (t & 7) << 3;
        const float* s0 = src + (size_t)(k0 + r) * 256 + n0 + c;
        float4 f0 = *(const float4*)s0;
        float4 f1 = *(const float4*)(s0 + 4);
        tile[r][c + 0] = f2bf(f0.x); tile[r][c + 1] = f2bf(f0.y);
        tile[r][c + 2] = f2bf(f0.z); tile[r][c + 3] = f2bf(f0.w);
        tile[r][c + 4] = f2bf(f1.x); tile[r][c + 5] = f2bf(f1.y);
        tile[r][c + 6] = f2bf(f1.z); tile[r][c + 7] = f2bf(f1.w);
    }
    __syncthreads();
    {
        int n = t >> 2, c = (t & 3) << 3;
        uint16_t tmp[8];
#pragma unroll
        for (int j = 0; j < 8; ++j) tmp[j] = tile[c + j][n];
        *(uint4*)&dst[(size_t)(k0 >> 5) * CHUNK_E + (size_t)(n0 + n) * 36 + c] = *(uint4*)tmp;
    }
}

// -------- GEMM: W resident in LDS, M-tiles barrier-free, fused epilogues --------
enum { EP_NONE = 0, EP_GELU_RMS = 1, EP_RESID_RMS = 2 };

struct GemmArgs {
    const uint16_t* A[4];
    const uint16_t* W[4];
    uint16_t* O[4];
};

template<int EPI, int K, int NT, bool AMUL>
__global__ __launch_bounds__(256, 1) void gemm3_k(
    GemmArgs ga,
    const float* __restrict__ bias, const float* __restrict__ resid,
    const uint16_t* __restrict__ mulg, const float* __restrict__ lnw,
    float* __restrict__ xout)
{
    constexpr int NC = K / 32;                       // chunks
    __shared__ __align__(16) uint16_t Ws[NC * CHUNK_E];
    __shared__ float rowsum[4][32];
    const int y = blockIdx.y;
    const uint16_t* __restrict__ A  = ga.A[y];
    const uint16_t* __restrict__ Wt = ga.W[y];
    uint16_t* __restrict__ O        = ga.O[y];
    const int t = threadIdx.x;
    const int w = t >> 6, lane = t & 63, l16 = lane & 15, lg = lane >> 4;
    const int m0base = blockIdx.x * (32 * NT);

    // ---- stage W (whole matrix) into LDS, one burst, one barrier ----
    constexpr int TOT16 = NC * (CHUNK_E / 8);        // 16-B slots
#pragma unroll
    for (int j = 0; j < (TOT16 + 255) / 256; ++j) {
        int s = j * 256 + t;
        if (s < TOT16) gl_lds16(Wt + (size_t)s * 8, Ws + (size_t)s * 8);
    }
    __syncthreads();

    for (int tt = 0; tt < NT; ++tt) {
        const int m0 = m0base + tt * 32;
        floatx4 acc[2][4];
#pragma unroll
        for (int i = 0; i < 2; ++i)
#pragma unroll
            for (int j = 0; j < 4; ++j) acc[i][j] = (floatx4){0.f, 0.f, 0.f, 0.f};

#pragma unroll
        for (int kc = 0; kc < NC; ++kc) {
            short8 aF[2];
#pragma unroll
            for (int rt = 0; rt < 2; ++rt) {
                size_t off = (size_t)(m0 + (rt << 4) + l16) * K + (kc << 5) + (lg << 3);
                if (!AMUL) {
                    aF[rt] = *(const short8*)(A + off);
                } else {
                    short8 u8 = *(const short8*)(A + off);
                    short8 g8 = *(const short8*)(mulg + off);
                    union { short8 s; uint16_t u[8]; } r, uu, gg;
                    uu.s = u8; gg.s = g8;
#pragma unroll
                    for (int j = 0; j < 8; ++j)
                        r.u[j] = f2bf(swishf(bf2f(gg.u[j])) * bf2f(uu.u[j]));
                    aF[rt] = r.s;
                }
            }
            short8 bF[4];
#pragma unroll
            for (int ct = 0; ct < 4; ++ct)
                bF[ct] = *(const short8*)&Ws[kc * CHUNK_E +
                         ((w << 6) + (ct << 4) + l16) * 36 + (lg << 3)];
#pragma unroll
            for (int rt = 0; rt < 2; ++rt)
#pragma unroll
                for (int ct = 0; ct < 4; ++ct)
                    acc[rt][ct] = __builtin_amdgcn_mfma_f32_16x16x32_bf16(
                        aF[rt], bF[ct], acc[rt][ct], 0, 0, 0);
        }

        // ---- epilogue ----
        float v[2][4][4];
#pragma unroll
        for (int rt = 0; rt < 2; ++rt)
#pragma unroll
            for (int ct = 0; ct < 4; ++ct)
#pragma unroll
                for (int r = 0; r < 4; ++r) {
                    int row = (rt << 4) + (lg << 2) + r;
                    int col = (w << 6) + (ct << 4) + l16;
                    size_t idx = (size_t)(m0 + row) * 256 + col;
                    float x = acc[rt][ct][r];
                    if (EPI == EP_GELU_RMS) { if (bias) x += bias[col]; x = geluf(x); }
                    if (EPI == EP_RESID_RMS) x += resid[idx];
                    v[rt][ct][r] = x;
                }

        if (EPI == EP_GELU_RMS || EPI == EP_RESID_RMS) {
#pragma unroll
            for (int rt = 0; rt < 2; ++rt)
#pragma unroll
                for (int r = 0; r < 4; ++r) {
                    float p = 0.f;
#pragma unroll
                    for (int ct = 0; ct < 4; ++ct) p += v[rt][ct][r] * v[rt][ct][r];
                    p += __shfl_xor(p, 1, 64); p += __shfl_xor(p, 2, 64);
                    p += __shfl_xor(p, 4, 64); p += __shfl_xor(p, 8, 64);
                    int row = (rt << 4) + (lg << 2) + r;
                    if (l16 == 0) rowsum[w][row] = p;
                }
            __syncthreads();
#pragma unroll
            for (int rt = 0; rt < 2; ++rt)
#pragma unroll
                for (int r = 0; r < 4; ++r) {
                    int row = (rt << 4) + (lg << 2) + r;
                    float tot = rowsum[0][row] + rowsum[1][row] + rowsum[2][row] + rowsum[3][row];
                    float rn = rsqrtf(tot * (1.f / 256.f) + 1e-6f);
#pragma unroll
                    for (int ct = 0; ct < 4; ++ct) {
                        int col = (w << 6) + (ct << 4) + l16;
                        size_t idx = (size_t)(m0 + row) * 256 + col;
                        float o = v[rt][ct][r] * rn * lnw[col];
                        O[idx] = f2bf(o);
                        if (xout) xout[idx] = o;
                    }
                }
            __syncthreads();   // protect rowsum reuse by next tile
        } else {
#pragma unroll
            for (int rt = 0; rt < 2; ++rt)
#pragma unroll
                for (int ct = 0; ct < 4; ++ct)
#pragma unroll
                    for (int r = 0; r < 4; ++r) {
                        int row = (rt << 4) + (lg << 2) + r;
                        int col = (w << 6) + (ct << 4) + l16;
                        O[(size_t)(m0 + row) * 256 + col] = f2bf(v[rt][ct][r]);
                    }
        }
    }
}

// ---------------- retention attention: 1 barrier, fused groupnorm + swish gate ----------------
struct GArg { float l2g[8]; };

__global__ __launch_bounds__(256) void attn_k(
    const uint16_t* __restrict__ q, const uint16_t* __restrict__ kbuf,
    const uint16_t* __restrict__ vbuf, const uint16_t* __restrict__ g,
    const float* __restrict__ gns, const float* __restrict__ gnb,
    uint16_t* __restrict__ out, GArg ga)
{
    __shared__ __align__(16) uint16_t QS[256][40];   // Q rows, then per-wave S-scratch (wave-private rows)
    __shared__ __align__(16) uint16_t Ks[256][40];
    __shared__ __align__(16) uint16_t Vt[32][264];
    const int b = blockIdx.x >> 3, h = blockIdx.x & 7;
    const float l2g = ga.l2g[h];
    const int t = threadIdx.x, w = t >> 6, lane = t & 63, l16 = lane & 15, lg = lane >> 4;
    const size_t base = ((size_t)b * 256) * 256 + (size_t)h * 32;

    {
        const uint4* qr = (const uint4*)(q + base + (size_t)t * 256);
        *(uint4*)&QS[t][0] = qr[0]; *(uint4*)&QS[t][8] = qr[1];
        *(uint4*)&QS[t][16] = qr[2]; *(uint4*)&QS[t][24] = qr[3];
        const uint4* kr = (const uint4*)(kbuf + base + (size_t)t * 256);
        *(uint4*)&Ks[t][0] = kr[0]; *(uint4*)&Ks[t][8] = kr[1];
        *(uint4*)&Ks[t][16] = kr[2]; *(uint4*)&Ks[t][24] = kr[3];
        union { uint4 v4[4]; uint16_t u[32]; } vv;
        const uint4* vr = (const uint4*)(vbuf + base + (size_t)t * 256);
        vv.v4[0] = vr[0]; vv.v4[1] = vr[1]; vv.v4[2] = vr[2]; vv.v4[3] = vr[3];
#pragma unroll
        for (int d = 0; d < 32; ++d) Vt[d][t] = vv.u[d];
    }
    __syncthreads();   // the ONLY barrier: K/V staged cross-wave

    short8 qF[4];
#pragma unroll
    for (int rt = 0; rt < 4; ++rt)
        qF[rt] = *(const short8*)&QS[(w << 6) + (rt << 4) + l16][lg << 3];

    floatx4 racc[4][2];
#pragma unroll
    for (int i = 0; i < 4; ++i) { racc[i][0] = (floatx4){0,0,0,0}; racc[i][1] = (floatx4){0,0,0,0}; }

    const float invsq = 0.17677669529663687f;
    for (int jt = 0; jt < 8; ++jt) {
        const int j0 = jt << 5;
        floatx4 sacc[4][2];
#pragma unroll
        for (int i = 0; i < 4; ++i) { sacc[i][0] = (floatx4){0,0,0,0}; sacc[i][1] = (floatx4){0,0,0,0}; }
        short8 kF[2];
#pragma unroll
        for (int ct = 0; ct < 2; ++ct)
            kF[ct] = *(const short8*)&Ks[j0 + (ct << 4) + l16][lg << 3];
#pragma unroll
        for (int rt = 0; rt < 4; ++rt)
#pragma unroll
            for (int ct = 0; ct < 2; ++ct)
                sacc[rt][ct] = __builtin_amdgcn_mfma_f32_16x16x32_bf16(
                    qF[rt], kF[ct], sacc[rt][ct], 0, 0, 0);
        // decay + causal mask -> wave-private S-scratch (no barrier needed)
#pragma unroll
        for (int rt = 0; rt < 4; ++rt)
#pragma unroll
            for (int ct = 0; ct < 2; ++ct)
#pragma unroll
                for (int r = 0; r < 4; ++r) {
                    int row = (rt << 4) + (lg << 2) + r;
                    int i = (w << 6) + row;
                    int j = j0 + (ct << 4) + l16;
                    float sv = 0.f;
                    if (i >= j)
                        sv = sacc[rt][ct][r] * invsq *
                             exp2f((float)((i >> 3) - (j >> 3)) * l2g);
                    QS[(w << 6) + row][(ct << 4) + l16] = f2bf(sv);
                }
        short8 vF[2];
#pragma unroll
        for (int ct = 0; ct < 2; ++ct)
            vF[ct] = *(const short8*)&Vt[(ct << 4) + l16][j0 + (lg << 3)];
#pragma unroll
        for (int rt = 0; rt < 4; ++rt) {
            short8 sF = *(const short8*)&QS[(w << 6) + (rt << 4) + l16][lg << 3];
#pragma unroll
            for (int ct = 0; ct < 2; ++ct)
                racc[rt][ct] = __builtin_amdgcn_mfma_f32_16x16x32_bf16(
                    sF, vF[ct], racc[rt][ct], 0, 0, 0);
        }
    }

#pragma unroll
    for (int rt = 0; rt < 4; ++rt)
#pragma unroll
        for (int r = 0; r < 4; ++r) {
            float v0 = racc[rt][0][r], v1 = racc[rt][1][r];
            float s1 = v0 + v1, s2 = v0 * v0 + v1 * v1;
            s1 += __shfl_xor(s1, 1, 64); s2 += __shfl_xor(s2, 1, 64);
            s1 += __shfl_xor(s1, 2, 64); s2 += __shfl_xor(s2, 2, 64);
            s1 += __shfl_xor(s1, 4, 64); s2 += __shfl_xor(s2, 4, 64);
            s1 += __shfl_xor(s1, 8, 64); s2 += __shfl_xor(s2, 8, 64);
            float mu = s1 * (1.f / 32.f);
            float var = s2 * (1.f / 32.f) - mu * mu;
            float rstd = rsqrtf(var + 1e-5f);
            int srow = (w << 6) + (rt << 4) + (lg << 2) + r;
            size_t obase = ((size_t)b * 256 + srow) * 256 + (size_t)h * 32;
#pragma unroll
            for (int ct = 0; ct < 2; ++ct) {
                int d = (ct << 4) + l16;
                float x = ct ? v1 : v0;
                float y = (x - mu) * rstd * gns[h * 32 + d] + gnb[h * 32 + d];
                float gv = swishf(bf2f(g[obase + d]));
                out[obase + d] = f2bf(y * gv);
            }
        }
}

// ---------------- final head: out = h @ hw2 + hb2 ----------------
__global__ __launch_bounds__(256) void head_out_k(
    const uint16_t* __restrict__ h, const float* __restrict__ w2,
    const float* __restrict__ b2, float* __restrict__ out)
{
    __shared__ float hr[8][260];
    int m0 = blockIdx.x << 3;
    int t = threadIdx.x;
    {
        int r = t >> 5, c = (t & 31) << 3;
        uint4 raw = *(const uint4*)(h + (size_t)(m0 + r) * 256 + c);
        const uint16_t* us = (const uint16_t*)&raw;
#pragma unroll
        for (int j = 0; j < 8; ++j) hr[r][c + j] = bf2f(us[j]);
    }
    __syncthreads();
    int r = t >> 5, n = t & 31;
    float acc = b2[n];
#pragma unroll 4
    for (int k = 0; k < 256; ++k) acc += hr[r][k] * w2[(size_t)k * 32 + n];
    out[(size_t)(m0 + r) * 32 + n] = acc;
}

// ---------------- host ----------------
extern "C" void kernel_launch(void* const* d_in, const int* in_sizes, int n_in,
                              void* d_out, int out_size, void* d_ws, size_t ws_size,
                              hipStream_t stream)
{
    const float* action = (const float*)d_in[0];
    const float* obs    = (const float*)d_in[1];
    const float* w_enc  = (const float*)d_in[2];
    const float* ln0    = (const float*)d_in[3];
    const float* wq1 = (const float*)d_in[4];
    const float* wk1 = (const float*)d_in[5];
    const float* wv1 = (const float*)d_in[6];
    const float* wg1 = (const float*)d_in[7];
    const float* wo1 = (const float*)d_in[8];
    const float* gns1 = (const float*)d_in[9];
    const float* gnb1 = (const float*)d_in[10];
    const float* ln1  = (const float*)d_in[11];
    const float* wq2 = (const float*)d_in[12];
    const float* wk2 = (const float*)d_in[13];
    const float* wv2 = (const float*)d_in[14];
    const float* wg2 = (const float*)d_in[15];
    const float* wo2 = (const float*)d_in[16];
    const float* gns2 = (const float*)d_in[17];
    const float* gnb2 = (const float*)d_in[18];
    const float* ln2  = (const float*)d_in[19];
    const float* swgp = (const float*)d_in[20];
    const float* sw1p = (const float*)d_in[21];
    const float* sw2p = (const float*)d_in[22];
    const float* ln3  = (const float*)d_in[23];
    const float* hw1  = (const float*)d_in[24];
    const float* hb1  = (const float*)d_in[25];
    const float* hln  = (const float*)d_in[26];
    const float* hw2  = (const float*)d_in[27];
    const float* hb2  = (const float*)d_in[28];
    float* outp = (float*)d_out;

    char* ws = (char*)d_ws;
    uint16_t* wt   = (uint16_t*)(ws + 0);            // 5,916,672 B padded bf16 weights
    uint16_t* actb = (uint16_t*)(ws + 6291456);
    uint16_t* obsb = (uint16_t*)(ws + 7340032);
    float*    xf   = (float*)   (ws + 15728640);
    uint16_t* xb   = (uint16_t*)(ws + 32505856);
    uint16_t* bq   = (uint16_t*)(ws + 40894464);
    uint16_t* bk   = (uint16_t*)(ws + 49283072);
    uint16_t* bv   = (uint16_t*)(ws + 57671680);
    uint16_t* bg   = (uint16_t*)(ws + 66060288);
    uint16_t* brg  = (uint16_t*)(ws + 74448896);     // end 82,837,504

    uint16_t* wtenc = wt;
    uint16_t* hw1t  = wt + CHUNK_E + (size_t)39 * MAT_E;
    auto WTp = [&](int ti, int s) { return wt + CHUNK_E + (size_t)(ti * 3 + s) * MAT_E; };

    GArg gaD;
    {
        const double a = log(1.0 / 32.0), bb = log(1.0 / 512.0);
        for (int hh = 0; hh < 8; ++hh) {
            double lg = a + (bb - a) * hh / 7.0;
            double gam = 1.0 - exp(lg);
            gaD.l2g[hh] = (float)(log(gam) / log(2.0));
        }
    }
    TArg ta;
    ta.src[0] = w_enc;
    ta.src[1] = wq1;  ta.src[2] = wk1;  ta.src[3] = wv1;  ta.src[4] = wg1;  ta.src[5] = wo1;
    ta.src[6] = wq2;  ta.src[7] = wk2;  ta.src[8] = wv2;  ta.src[9] = wg2;  ta.src[10] = wo2;
    ta.src[11] = swgp; ta.src[12] = sw1p; ta.src[13] = sw2p; ta.src[14] = hw1;

    tpose_k<<<dim3(4, 8, 41), 256, 0, stream>>>(ta, wt);
    cvt_k<<<512, 256, 0, stream>>>(action, actb, 131072);
    cvt_k<<<4096, 256, 0, stream>>>(obs, obsb, 1048576);

    dim3 TB(256);
    auto g1 = [&](const uint16_t* A, const uint16_t* W, uint16_t* O) {
        GemmArgs g; g.A[0] = A; g.W[0] = W; g.O[0] = O;
        g.A[1] = g.A[2] = g.A[3] = A; g.W[1] = g.W[2] = g.W[3] = W;
        g.O[1] = g.O[2] = g.O[3] = O;
        return g;
    };

    // encoder: x = rmsnorm(gelu(action @ w_enc), ln0)
    gemm3_k<EP_GELU_RMS, 32, 2, false><<<dim3(256, 1), TB, 0, stream>>>(
        g1(actb, wtenc, xb), nullptr, nullptr, nullptr, ln0, xf);

    for (int b3 = 0; b3 < 3; ++b3) {
        {   // retention 1 (self): fused q,k,v,g — 256 blocks, 8 tiles each
            GemmArgs g;
            g.A[0] = g.A[1] = g.A[2] = g.A[3] = xb;
            g.W[0] = WTp(0, b3); g.W[1] = WTp(1, b3); g.W[2] = WTp(2, b3); g.W[3] = WTp(3, b3);
            g.O[0] = bq; g.O[1] = bk; g.O[2] = bv; g.O[3] = bg;
            gemm3_k<EP_NONE, 256, 8, false><<<dim3(64, 4), TB, 0, stream>>>(
                g, nullptr, nullptr, nullptr, nullptr, nullptr);
        }
        attn_k<<<512, TB, 0, stream>>>(bq, bk, bv, bg, gns1 + b3 * 256, gnb1 + b3 * 256, brg, gaD);
        gemm3_k<EP_RESID_RMS, 256, 2, false><<<dim3(256, 1), TB, 0, stream>>>(
            g1(brg, WTp(4, b3), xb), nullptr, xf, nullptr, ln1 + b3 * 256, xf);
        {   // retention 2 (cross): q,g from obs_rep; k,v from x
            GemmArgs g;
            g.A[0] = obsb; g.A[1] = xb; g.A[2] = xb; g.A[3] = obsb;
            g.W[0] = WTp(5, b3); g.W[1] = WTp(6, b3); g.W[2] = WTp(7, b3); g.W[3] = WTp(8, b3);
            g.O[0] = bq; g.O[1] = bk; g.O[2] = bv; g.O[3] = bg;
            gemm3_k<EP_NONE, 256, 8, false><<<dim3(64, 4), TB, 0, stream>>>(
                g, nullptr, nullptr, nullptr, nullptr, nullptr);
        }
        attn_k<<<512, TB, 0, stream>>>(bq, bk, bv, bg, gns2 + b3 * 256, gnb2 + b3 * 256, brg, gaD);
        gemm3_k<EP_RESID_RMS, 256, 2, false><<<dim3(256, 1), TB, 0, stream>>>(
            g1(brg, WTp(9, b3), xb), nullptr, obs, nullptr, ln2 + b3 * 256, xf);
        {   // swiglu: gate (swg) and up (sw1) fused — 256 blocks, 4 tiles each
            GemmArgs g;
            g.A[0] = g.A[1] = xb;       g.A[2] = g.A[3] = xb;
            g.W[0] = WTp(10, b3); g.W[1] = WTp(11, b3); g.W[2] = g.W[0]; g.W[3] = g.W[1];
            g.O[0] = bq; g.O[1] = bv; g.O[2] = bq; g.O[3] = bv;
            gemm3_k<EP_NONE, 256, 4, false><<<dim3(128, 2), TB, 0, stream>>>(
                g, nullptr, nullptr, nullptr, nullptr, nullptr);
        }
        // down-proj with A-side swish-gate fusion: A_eff = swish(bq)*bv
        gemm3_k<EP_RESID_RMS, 256, 2, true><<<dim3(256, 1), TB, 0, stream>>>(
            g1(bv, WTp(12, b3), xb), nullptr, xf, bq, ln3 + b3 * 256, xf);
    }
    // head
    gemm3_k<EP_GELU_RMS, 256, 2, false><<<dim3(256, 1), TB, 0, stream>>>(
        g1(xb, hw1t, bq), hb1, nullptr, nullptr, hln, nullptr);
    head_out_k<<<2048, TB, 0, stream>>>(bq, hw2, hb2, outp);
}

// Round 4
// 725.427 us; speedup vs baseline: 1.0445x; 1.0445x over previous
//
#include <hip/hip_runtime.h>
#include <cstdint>
#include <cmath>

typedef __attribute__((ext_vector_type(8))) short short8;
typedef __attribute__((ext_vector_type(4))) float floatx4;

#define DEV static __device__ __forceinline__

DEV float bf2f(uint16_t u) {
    union { uint32_t i; float f; } v; v.i = ((uint32_t)u) << 16; return v.f;
}
DEV uint16_t f2bf(float f) {
    union { float f; uint32_t i; } v; v.f = f;
    uint32_t r = (v.i + 0x7FFFu + ((v.i >> 16) & 1u)) >> 16;
    return (uint16_t)r;
}
DEV float swishf(float x) { return x / (1.f + __expf(-x)); }
DEV float geluf(float x) {
    const float c = 0.7978845608028654f;
    float t = tanhf(c * (x + 0.044715f * x * x * x));
    return 0.5f * x * (1.f + t);
}

// W packing: per 32-K chunk, layout [n(256)][32] contiguous (no pad).
// B-fragment for (wave,ct) = rows ct*16..+15 of a chunk = contiguous 1 KB -> one
// coalesced global_load_dwordx4 per fragment, straight from L2. No LDS needed.
#define CHUNK_E 8192
#define MAT_E   65536   // 8 chunks

// ---------------- convert fp32 -> bf16 (flat) ----------------
__global__ __launch_bounds__(256) void cvt_k(const float* __restrict__ src,
                                             uint16_t* __restrict__ dst, int n4) {
    int i = blockIdx.x * 256 + threadIdx.x;
    if (i >= n4) return;
    float4 f = ((const float4*)src)[i];
    uint16_t tmp[4] = { f2bf(f.x), f2bf(f.y), f2bf(f.z), f2bf(f.w) };
    ((uint2*)dst)[i] = *(uint2*)tmp;
}

// ---- transpose+convert: W[K,N=256] fp32 -> packed chunks [kc][n][32] bf16 ----
struct TArg { const float* src[15]; };

__global__ __launch_bounds__(256) void tpose_k(TArg ta, uint16_t* __restrict__ arena) {
    int z = blockIdx.z;
    const float* src; uint16_t* dst;
    if (z == 0) {
        if (blockIdx.y) return;
        src = ta.src[0]; dst = arena;                            // w_enc [32,256]
    } else if (z <= 39) {
        int q = z - 1; int ti = q / 3, s = q % 3;
        src = ta.src[1 + ti] + (size_t)s * 65536;
        dst = arena + CHUNK_E + (size_t)(ti * 3 + s) * MAT_E;
    } else {
        src = ta.src[14]; dst = arena + CHUNK_E + (size_t)39 * MAT_E;   // hw1
    }
    int k0 = blockIdx.y << 5;   // K chunk (32)
    int n0 = blockIdx.x << 6;   // N tile (64)
    __shared__ __align__(16) uint16_t tile[32][72];
    int t = threadIdx.x;
    {
        int r = t >> 3, c = (t & 7) << 3;
        const float* s0 = src + (size_t)(k0 + r) * 256 + n0 + c;
        float4 f0 = *(const float4*)s0;
        float4 f1 = *(const float4*)(s0 + 4);
        tile[r][c + 0] = f2bf(f0.x); tile[r][c + 1] = f2bf(f0.y);
        tile[r][c + 2] = f2bf(f0.z); tile[r][c + 3] = f2bf(f0.w);
        tile[r][c + 4] = f2bf(f1.x); tile[r][c + 5] = f2bf(f1.y);
        tile[r][c + 6] = f2bf(f1.z); tile[r][c + 7] = f2bf(f1.w);
    }
    __syncthreads();
    {
        int n = t >> 2, c = (t & 3) << 3;
        uint16_t tmp[8];
#pragma unroll
        for (int j = 0; j < 8; ++j) tmp[j] = tile[c + j][n];
        *(uint4*)&dst[(size_t)(k0 >> 5) * CHUNK_E + (size_t)(n0 + n) * 32 + c] = *(uint4*)tmp;
    }
}

// -------- GEMM: zero-LDS, fragments direct from L2, fused epilogues --------
// grid = 256 blocks, block b <-> rows b*64..b*64+63 for EVERY stage (L2/XCD locality).
enum { EP_NONE = 0, EP_GELU_RMS = 1, EP_RESID_RMS = 2, EP_SWIGLU = 3 };

struct GemmArgs {
    const uint16_t* A[4];
    const uint16_t* W[4];
    uint16_t* O[4];
};

template<int EPI, int K, int NMAT>
__global__ __launch_bounds__(256) void gemm4_k(
    GemmArgs ga,
    const float* __restrict__ bias, const float* __restrict__ resid,
    const float* __restrict__ lnw, float* __restrict__ xout)
{
    __shared__ float rowsum[4][64];
    const int t = threadIdx.x;
    const int w = t >> 6, lane = t & 63, l16 = lane & 15, lg = lane >> 4;
    const int m0 = blockIdx.x * 64;
    constexpr int NC = K / 32;

    float sv[4][4][4];   // swiglu gate stash (registers)

#pragma unroll
    for (int mat = 0; mat < NMAT; ++mat) {
        const uint16_t* __restrict__ A  = ga.A[mat];
        const uint16_t* __restrict__ Wt = ga.W[mat];
        uint16_t* __restrict__ O        = ga.O[mat];

        floatx4 acc[4][4];
#pragma unroll
        for (int i = 0; i < 4; ++i)
#pragma unroll
            for (int j = 0; j < 4; ++j) acc[i][j] = (floatx4){0.f, 0.f, 0.f, 0.f};

#pragma unroll
        for (int kc = 0; kc < NC; ++kc) {
            short8 aF[4], bF[4];
#pragma unroll
            for (int rt = 0; rt < 4; ++rt)
                aF[rt] = *(const short8*)(A + (size_t)(m0 + (rt << 4) + l16) * K +
                                          (kc << 5) + (lg << 3));
#pragma unroll
            for (int ct = 0; ct < 4; ++ct)
                bF[ct] = *(const short8*)(Wt + (size_t)kc * CHUNK_E +
                                          (size_t)((w << 6) + (ct << 4) + l16) * 32 + (lg << 3));
#pragma unroll
            for (int rt = 0; rt < 4; ++rt)
#pragma unroll
                for (int ct = 0; ct < 4; ++ct)
                    acc[rt][ct] = __builtin_amdgcn_mfma_f32_16x16x32_bf16(
                        aF[rt], bF[ct], acc[rt][ct], 0, 0, 0);
        }

        // ---- epilogue ----
        // C layout: row_local = rt*16 + lg*4 + r (0..63), col = w*64 + ct*16 + l16
        if (EPI == EP_SWIGLU && mat == 0) {
#pragma unroll
            for (int rt = 0; rt < 4; ++rt)
#pragma unroll
                for (int ct = 0; ct < 4; ++ct)
#pragma unroll
                    for (int r = 0; r < 4; ++r) sv[rt][ct][r] = acc[rt][ct][r];
            continue;
        }

        float v[4][4][4];
#pragma unroll
        for (int rt = 0; rt < 4; ++rt)
#pragma unroll
            for (int ct = 0; ct < 4; ++ct)
#pragma unroll
                for (int r = 0; r < 4; ++r) {
                    int row = (rt << 4) + (lg << 2) + r;
                    int col = (w << 6) + (ct << 4) + l16;
                    size_t idx = (size_t)(m0 + row) * 256 + col;
                    float x = acc[rt][ct][r];
                    if (EPI == EP_GELU_RMS) { if (bias) x += bias[col]; x = geluf(x); }
                    if (EPI == EP_RESID_RMS) x += resid[idx];
                    if (EPI == EP_SWIGLU) x *= swishf(sv[rt][ct][r]);
                    v[rt][ct][r] = x;
                }

        if (EPI == EP_GELU_RMS || EPI == EP_RESID_RMS) {
#pragma unroll
            for (int rt = 0; rt < 4; ++rt)
#pragma unroll
                for (int r = 0; r < 4; ++r) {
                    float p = 0.f;
#pragma unroll
                    for (int ct = 0; ct < 4; ++ct) p += v[rt][ct][r] * v[rt][ct][r];
                    p += __shfl_xor(p, 1, 64); p += __shfl_xor(p, 2, 64);
                    p += __shfl_xor(p, 4, 64); p += __shfl_xor(p, 8, 64);
                    int row = (rt << 4) + (lg << 2) + r;
                    if (l16 == 0) rowsum[w][row] = p;
                }
            __syncthreads();
#pragma unroll
            for (int rt = 0; rt < 4; ++rt)
#pragma unroll
                for (int r = 0; r < 4; ++r) {
                    int row = (rt << 4) + (lg << 2) + r;
                    float tot = rowsum[0][row] + rowsum[1][row] + rowsum[2][row] + rowsum[3][row];
                    float rn = rsqrtf(tot * (1.f / 256.f) + 1e-6f);
#pragma unroll
                    for (int ct = 0; ct < 4; ++ct) {
                        int col = (w << 6) + (ct << 4) + l16;
                        size_t idx = (size_t)(m0 + row) * 256 + col;
                        float o = v[rt][ct][r] * rn * lnw[col];
                        O[idx] = f2bf(o);
                        if (xout) xout[idx] = o;
                    }
                }
        } else {
#pragma unroll
            for (int rt = 0; rt < 4; ++rt)
#pragma unroll
                for (int ct = 0; ct < 4; ++ct)
#pragma unroll
                    for (int r = 0; r < 4; ++r) {
                        int row = (rt << 4) + (lg << 2) + r;
                        int col = (w << 6) + (ct << 4) + l16;
                        O[(size_t)(m0 + row) * 256 + col] = f2bf(v[rt][ct][r]);
                    }
        }
    }
}

// ---------------- retention attention: 1 barrier, fused groupnorm + swish gate ----------------
struct GArg { float l2g[8]; };

__global__ __launch_bounds__(256) void attn_k(
    const uint16_t* __restrict__ q, const uint16_t* __restrict__ kbuf,
    const uint16_t* __restrict__ vbuf, const uint16_t* __restrict__ g,
    const float* __restrict__ gns, const float* __restrict__ gnb,
    uint16_t* __restrict__ out, GArg ga)
{
    __shared__ __align__(16) uint16_t QS[256][40];
    __shared__ __align__(16) uint16_t Ks[256][40];
    __shared__ __align__(16) uint16_t Vt[32][264];
    const int b = blockIdx.x & 63, h = blockIdx.x >> 6;   // batch-major for XCD locality
    const float l2g = ga.l2g[h];
    const int t = threadIdx.x, w = t >> 6, lane = t & 63, l16 = lane & 15, lg = lane >> 4;
    const size_t base = ((size_t)b * 256) * 256 + (size_t)h * 32;

    {
        const uint4* qr = (const uint4*)(q + base + (size_t)t * 256);
        *(uint4*)&QS[t][0] = qr[0]; *(uint4*)&QS[t][8] = qr[1];
        *(uint4*)&QS[t][16] = qr[2]; *(uint4*)&QS[t][24] = qr[3];
        const uint4* kr = (const uint4*)(kbuf + base + (size_t)t * 256);
        *(uint4*)&Ks[t][0] = kr[0]; *(uint4*)&Ks[t][8] = kr[1];
        *(uint4*)&Ks[t][16] = kr[2]; *(uint4*)&Ks[t][24] = kr[3];
        union { uint4 v4[4]; uint16_t u[32]; } vv;
        const uint4* vr = (const uint4*)(vbuf + base + (size_t)t * 256);
        vv.v4[0] = vr[0]; vv.v4[1] = vr[1]; vv.v4[2] = vr[2]; vv.v4[3] = vr[3];
#pragma unroll
        for (int d = 0; d < 32; ++d) Vt[d][t] = vv.u[d];
    }
    __syncthreads();   // the only barrier

    short8 qF[4];
#pragma unroll
    for (int rt = 0; rt < 4; ++rt)
        qF[rt] = *(const short8*)&QS[(w << 6) + (rt << 4) + l16][lg << 3];

    floatx4 racc[4][2];
#pragma unroll
    for (int i = 0; i < 4; ++i) { racc[i][0] = (floatx4){0,0,0,0}; racc[i][1] = (floatx4){0,0,0,0}; }

    const float invsq = 0.17677669529663687f;
    for (int jt = 0; jt < 8; ++jt) {
        const int j0 = jt << 5;
        floatx4 sacc[4][2];
#pragma unroll
        for (int i = 0; i < 4; ++i) { sacc[i][0] = (floatx4){0,0,0,0}; sacc[i][1] = (floatx4){0,0,0,0}; }
        short8 kF[2];
#pragma unroll
        for (int ct = 0; ct < 2; ++ct)
            kF[ct] = *(const short8*)&Ks[j0 + (ct << 4) + l16][lg << 3];
#pragma unroll
        for (int rt = 0; rt < 4; ++rt)
#pragma unroll
            for (int ct = 0; ct < 2; ++ct)
                sacc[rt][ct] = __builtin_amdgcn_mfma_f32_16x16x32_bf16(
                    qF[rt], kF[ct], sacc[rt][ct], 0, 0, 0);
        // decay + causal mask -> wave-private S-scratch rows (no barrier)
#pragma unroll
        for (int rt = 0; rt < 4; ++rt)
#pragma unroll
            for (int ct = 0; ct < 2; ++ct)
#pragma unroll
                for (int r = 0; r < 4; ++r) {
                    int row = (rt << 4) + (lg << 2) + r;
                    int i = (w << 6) + row;
                    int j = j0 + (ct << 4) + l16;
                    float svv = 0.f;
                    if (i >= j)
                        svv = sacc[rt][ct][r] * invsq *
                              exp2f((float)((i >> 3) - (j >> 3)) * l2g);
                    QS[(w << 6) + row][(ct << 4) + l16] = f2bf(svv);
                }
        short8 vF[2];
#pragma unroll
        for (int ct = 0; ct < 2; ++ct)
            vF[ct] = *(const short8*)&Vt[(ct << 4) + l16][j0 + (lg << 3)];
#pragma unroll
        for (int rt = 0; rt < 4; ++rt) {
            short8 sF = *(const short8*)&QS[(w << 6) + (rt << 4) + l16][lg << 3];
#pragma unroll
            for (int ct = 0; ct < 2; ++ct)
                racc[rt][ct] = __builtin_amdgcn_mfma_f32_16x16x32_bf16(
                    sF, vF[ct], racc[rt][ct], 0, 0, 0);
        }
    }

#pragma unroll
    for (int rt = 0; rt < 4; ++rt)
#pragma unroll
        for (int r = 0; r < 4; ++r) {
            float v0 = racc[rt][0][r], v1 = racc[rt][1][r];
            float s1 = v0 + v1, s2 = v0 * v0 + v1 * v1;
            s1 += __shfl_xor(s1, 1, 64); s2 += __shfl_xor(s2, 1, 64);
            s1 += __shfl_xor(s1, 2, 64); s2 += __shfl_xor(s2, 2, 64);
            s1 += __shfl_xor(s1, 4, 64); s2 += __shfl_xor(s2, 4, 64);
            s1 += __shfl_xor(s1, 8, 64); s2 += __shfl_xor(s2, 8, 64);
            float mu = s1 * (1.f / 32.f);
            float var = s2 * (1.f / 32.f) - mu * mu;
            float rstd = rsqrtf(var + 1e-5f);
            int srow = (w << 6) + (rt << 4) + (lg << 2) + r;
            size_t obase = ((size_t)b * 256 + srow) * 256 + (size_t)h * 32;
#pragma unroll
            for (int ct = 0; ct < 2; ++ct) {
                int d = (ct << 4) + l16;
                float x = ct ? v1 : v0;
                float y = (x - mu) * rstd * gns[h * 32 + d] + gnb[h * 32 + d];
                float gv = swishf(bf2f(g[obase + d]));
                out[obase + d] = f2bf(y * gv);
            }
        }
}

// ---------------- final head: out = h @ hw2 + hb2 ----------------
__global__ __launch_bounds__(256) void head_out_k(
    const uint16_t* __restrict__ h, const float* __restrict__ w2,
    const float* __restrict__ b2, float* __restrict__ out)
{
    __shared__ float hr[8][260];
    int m0 = blockIdx.x << 3;
    int t = threadIdx.x;
    {
        int r = t >> 5, c = (t & 31) << 3;
        uint4 raw = *(const uint4*)(h + (size_t)(m0 + r) * 256 + c);
        const uint16_t* us = (const uint16_t*)&raw;
#pragma unroll
        for (int j = 0; j < 8; ++j) hr[r][c + j] = bf2f(us[j]);
    }
    __syncthreads();
    int r = t >> 5, n = t & 31;
    float acc = b2[n];
#pragma unroll 4
    for (int k = 0; k < 256; ++k) acc += hr[r][k] * w2[(size_t)k * 32 + n];
    out[(size_t)(m0 + r) * 32 + n] = acc;
}

// ---------------- host ----------------
extern "C" void kernel_launch(void* const* d_in, const int* in_sizes, int n_in,
                              void* d_out, int out_size, void* d_ws, size_t ws_size,
                              hipStream_t stream)
{
    const float* action = (const float*)d_in[0];
    const float* obs    = (const float*)d_in[1];
    const float* w_enc  = (const float*)d_in[2];
    const float* ln0    = (const float*)d_in[3];
    const float* wq1 = (const float*)d_in[4];
    const float* wk1 = (const float*)d_in[5];
    const float* wv1 = (const float*)d_in[6];
    const float* wg1 = (const float*)d_in[7];
    const float* wo1 = (const float*)d_in[8];
    const float* gns1 = (const float*)d_in[9];
    const float* gnb1 = (const float*)d_in[10];
    const float* ln1  = (const float*)d_in[11];
    const float* wq2 = (const float*)d_in[12];
    const float* wk2 = (const float*)d_in[13];
    const float* wv2 = (const float*)d_in[14];
    const float* wg2 = (const float*)d_in[15];
    const float* wo2 = (const float*)d_in[16];
    const float* gns2 = (const float*)d_in[17];
    const float* gnb2 = (const float*)d_in[18];
    const float* ln2  = (const float*)d_in[19];
    const float* swgp = (const float*)d_in[20];
    const float* sw1p = (const float*)d_in[21];
    const float* sw2p = (const float*)d_in[22];
    const float* ln3  = (const float*)d_in[23];
    const float* hw1  = (const float*)d_in[24];
    const float* hb1  = (const float*)d_in[25];
    const float* hln  = (const float*)d_in[26];
    const float* hw2  = (const float*)d_in[27];
    const float* hb2  = (const float*)d_in[28];
    float* outp = (float*)d_out;

    char* ws = (char*)d_ws;
    uint16_t* wt   = (uint16_t*)(ws + 0);
    uint16_t* actb = (uint16_t*)(ws + 6291456);
    uint16_t* obsb = (uint16_t*)(ws + 7340032);
    float*    xf   = (float*)   (ws + 15728640);
    uint16_t* xb   = (uint16_t*)(ws + 32505856);
    uint16_t* bq   = (uint16_t*)(ws + 40894464);
    uint16_t* bk   = (uint16_t*)(ws + 49283072);
    uint16_t* bv   = (uint16_t*)(ws + 57671680);
    uint16_t* bg   = (uint16_t*)(ws + 66060288);
    uint16_t* brg  = (uint16_t*)(ws + 74448896);

    uint16_t* wtenc = wt;
    uint16_t* hw1t  = wt + CHUNK_E + (size_t)39 * MAT_E;
    auto WTp = [&](int ti, int s) { return wt + CHUNK_E + (size_t)(ti * 3 + s) * MAT_E; };

    GArg gaD;
    {
        const double a = log(1.0 / 32.0), bb = log(1.0 / 512.0);
        for (int hh = 0; hh < 8; ++hh) {
            double lg = a + (bb - a) * hh / 7.0;
            double gam = 1.0 - exp(lg);
            gaD.l2g[hh] = (float)(log(gam) / log(2.0));
        }
    }
    TArg ta;
    ta.src[0] = w_enc;
    ta.src[1] = wq1;  ta.src[2] = wk1;  ta.src[3] = wv1;  ta.src[4] = wg1;  ta.src[5] = wo1;
    ta.src[6] = wq2;  ta.src[7] = wk2;  ta.src[8] = wv2;  ta.src[9] = wg2;  ta.src[10] = wo2;
    ta.src[11] = swgp; ta.src[12] = sw1p; ta.src[13] = sw2p; ta.src[14] = hw1;

    tpose_k<<<dim3(4, 8, 41), 256, 0, stream>>>(ta, wt);
    cvt_k<<<512, 256, 0, stream>>>(action, actb, 131072);
    cvt_k<<<4096, 256, 0, stream>>>(obs, obsb, 1048576);

    dim3 TB(256), GB(256);
    auto g1 = [&](const uint16_t* A, const uint16_t* W, uint16_t* O) {
        GemmArgs g; g.A[0] = A; g.W[0] = W; g.O[0] = O;
        g.A[1] = g.A[2] = g.A[3] = A; g.W[1] = g.W[2] = g.W[3] = W;
        g.O[1] = g.O[2] = g.O[3] = O;
        return g;
    };

    // encoder: x = rmsnorm(gelu(action @ w_enc), ln0)
    gemm4_k<EP_GELU_RMS, 32, 1><<<GB, TB, 0, stream>>>(
        g1(actb, wtenc, xb), nullptr, nullptr, ln0, xf);

    for (int b3 = 0; b3 < 3; ++b3) {
        {   // retention 1 (self): q,k,v,g in-block (A read once, rows stay on-CU)
            GemmArgs g;
            g.A[0] = g.A[1] = g.A[2] = g.A[3] = xb;
            g.W[0] = WTp(0, b3); g.W[1] = WTp(1, b3); g.W[2] = WTp(2, b3); g.W[3] = WTp(3, b3);
            g.O[0] = bq; g.O[1] = bk; g.O[2] = bv; g.O[3] = bg;
            gemm4_k<EP_NONE, 256, 4><<<GB, TB, 0, stream>>>(
                g, nullptr, nullptr, nullptr, nullptr);
        }
        attn_k<<<512, TB, 0, stream>>>(bq, bk, bv, bg, gns1 + b3 * 256, gnb1 + b3 * 256, brg, gaD);
        gemm4_k<EP_RESID_RMS, 256, 1><<<GB, TB, 0, stream>>>(
            g1(brg, WTp(4, b3), xb), nullptr, xf, ln1 + b3 * 256, xf);
        {   // retention 2 (cross): q,g from obs_rep; k,v from x
            GemmArgs g;
            g.A[0] = obsb; g.A[1] = xb; g.A[2] = xb; g.A[3] = obsb;
            g.W[0] = WTp(5, b3); g.W[1] = WTp(6, b3); g.W[2] = WTp(7, b3); g.W[3] = WTp(8, b3);
            g.O[0] = bq; g.O[1] = bk; g.O[2] = bv; g.O[3] = bg;
            gemm4_k<EP_NONE, 256, 4><<<GB, TB, 0, stream>>>(
                g, nullptr, nullptr, nullptr, nullptr);
        }
        attn_k<<<512, TB, 0, stream>>>(bq, bk, bv, bg, gns2 + b3 * 256, gnb2 + b3 * 256, brg, gaD);
        gemm4_k<EP_RESID_RMS, 256, 1><<<GB, TB, 0, stream>>>(
            g1(brg, WTp(9, b3), xb), nullptr, obs, ln2 + b3 * 256, xf);
        {   // swiglu: gate stashed in registers, store swish(gate)*up directly
            GemmArgs g;
            g.A[0] = g.A[1] = xb; g.A[2] = g.A[3] = xb;
            g.W[0] = WTp(10, b3); g.W[1] = WTp(11, b3); g.W[2] = g.W[0]; g.W[3] = g.W[1];
            g.O[0] = bk; g.O[1] = bk; g.O[2] = g.O[3] = bk;
            gemm4_k<EP_SWIGLU, 256, 2><<<GB, TB, 0, stream>>>(
                g, nullptr, nullptr, nullptr, nullptr);
        }
        gemm4_k<EP_RESID_RMS, 256, 1><<<GB, TB, 0, stream>>>(
            g1(bk, WTp(12, b3), xb), nullptr, xf, ln3 + b3 * 256, xf);
    }
    // head
    gemm4_k<EP_GELU_RMS, 256, 1><<<GB, TB, 0, stream>>>(
        g1(xb, hw1t, bq), hb1, nullptr, hln, nullptr);
    head_out_k<<<2048, TB, 0, stream>>>(bq, hw2, hb2, outp);
}

// Round 5
// 709.089 us; speedup vs baseline: 1.0686x; 1.0230x over previous
//
#include <hip/hip_runtime.h>
#include <cstdint>
#include <cmath>

typedef __attribute__((ext_vector_type(8))) short short8;
typedef __attribute__((ext_vector_type(4))) float floatx4;

#define DEV static __device__ __forceinline__

DEV float bf2f(uint16_t u) {
    union { uint32_t i; float f; } v; v.i = ((uint32_t)u) << 16; return v.f;
}
DEV uint16_t f2bf(float f) {
    union { float f; uint32_t i; } v; v.f = f;
    uint32_t r = (v.i + 0x7FFFu + ((v.i >> 16) & 1u)) >> 16;
    return (uint16_t)r;
}
DEV float swishf(float x) { return x / (1.f + __expf(-x)); }
DEV float geluf(float x) {
    const float c = 0.7978845608028654f;
    float t = tanhf(c * (x + 0.044715f * x * x * x));
    return 0.5f * x * (1.f + t);
}

// W packing: per 32-K chunk, layout [n(256)][32] contiguous. A wave's B-fragment
// is a contiguous 1 KB region -> one coalesced dwordx4 load/lane from L2.
#define CHUNK_E 8192
#define MAT_E   65536   // 8 chunks

// ---------------- convert fp32 -> bf16 (flat) ----------------
__global__ __launch_bounds__(256) void cvt_k(const float* __restrict__ src,
                                             uint16_t* __restrict__ dst, int n4) {
    int i = blockIdx.x * 256 + threadIdx.x;
    if (i >= n4) return;
    float4 f = ((const float4*)src)[i];
    uint16_t tmp[4] = { f2bf(f.x), f2bf(f.y), f2bf(f.z), f2bf(f.w) };
    ((uint2*)dst)[i] = *(uint2*)tmp;
}

// ---- transpose+convert: W[K,N=256] fp32 -> packed chunks [kc][n][32] bf16 ----
struct TArg { const float* src[15]; };

__global__ __launch_bounds__(256) void tpose_k(TArg ta, uint16_t* __restrict__ arena) {
    int z = blockIdx.z;
    const float* src; uint16_t* dst;
    if (z == 0) {
        if (blockIdx.y) return;
        src = ta.src[0]; dst = arena;                            // w_enc [32,256]
    } else if (z <= 39) {
        int q = z - 1; int ti = q / 3, s = q % 3;
        src = ta.src[1 + ti] + (size_t)s * 65536;
        dst = arena + CHUNK_E + (size_t)(ti * 3 + s) * MAT_E;
    } else {
        src = ta.src[14]; dst = arena + CHUNK_E + (size_t)39 * MAT_E;   // hw1
    }
    int k0 = blockIdx.y << 5;   // K chunk (32)
    int n0 = blockIdx.x << 6;   // N tile (64)
    __shared__ __align__(16) uint16_t tile[32][72];
    int t = threadIdx.x;
    {
        int r = t >> 3, c = (t & 7) << 3;
        const float* s0 = src + (size_t)(k0 + r) * 256 + n0 + c;
        float4 f0 = *(const float4*)s0;
        float4 f1 = *(const float4*)(s0 + 4);
        tile[r][c + 0] = f2bf(f0.x); tile[r][c + 1] = f2bf(f0.y);
        tile[r][c + 2] = f2bf(f0.z); tile[r][c + 3] = f2bf(f0.w);
        tile[r][c + 4] = f2bf(f1.x); tile[r][c + 5] = f2bf(f1.y);
        tile[r][c + 6] = f2bf(f1.z); tile[r][c + 7] = f2bf(f1.w);
    }
    __syncthreads();
    {
        int n = t >> 2, c = (t & 3) << 3;
        uint16_t tmp[8];
#pragma unroll
        for (int j = 0; j < 8; ++j) tmp[j] = tile[c + j][n];
        *(uint4*)&dst[(size_t)(k0 >> 5) * CHUNK_E + (size_t)(n0 + n) * 32 + c] = *(uint4*)tmp;
    }
}

// -------- GEMM v5: zero-LDS main loop, 32-row tiles, high occupancy --------
// Block = 4 waves, 32 rows x 256 cols (wave w owns cols w*64..+63).
// grid.x = 512 row-tiles; grid.y picks the matrix (qkvg fusion) -> up to
// 2048 blocks = 8 blocks/CU = latency hiding via TLP. No barriers in main loop.
enum { EP_NONE = 0, EP_GELU_RMS = 1, EP_RESID_RMS = 2, EP_SWIGLU = 3 };

struct GemmArgs {
    const uint16_t* A[4];
    const uint16_t* W[4];
    uint16_t* O[4];
};

template<int EPI, int K, int NMAT>
__global__ __launch_bounds__(256) void gemm5_k(
    GemmArgs ga,
    const float* __restrict__ bias, const float* __restrict__ resid,
    const float* __restrict__ lnw, float* __restrict__ xout)
{
    __shared__ float rowsum[4][32];
    const int t = threadIdx.x;
    const int w = t >> 6, lane = t & 63, l16 = lane & 15, lg = lane >> 4;
    const int m0 = blockIdx.x * 32;
    constexpr int NC = K / 32;

    float sv[2][4][4];   // swiglu gate stash

#pragma unroll
    for (int m = 0; m < NMAT; ++m) {
        const int mi = blockIdx.y * NMAT + m;
        const uint16_t* __restrict__ A  = ga.A[mi];
        const uint16_t* __restrict__ Wt = ga.W[mi];
        uint16_t* __restrict__ O        = ga.O[mi];

        floatx4 acc[2][4];
#pragma unroll
        for (int i = 0; i < 2; ++i)
#pragma unroll
            for (int j = 0; j < 4; ++j) acc[i][j] = (floatx4){0.f, 0.f, 0.f, 0.f};

#pragma unroll
        for (int kc = 0; kc < NC; ++kc) {
            short8 aF[2], bF[4];
#pragma unroll
            for (int rt = 0; rt < 2; ++rt)
                aF[rt] = *(const short8*)(A + (size_t)(m0 + (rt << 4) + l16) * K +
                                          (kc << 5) + (lg << 3));
#pragma unroll
            for (int ct = 0; ct < 4; ++ct)
                bF[ct] = *(const short8*)(Wt + (size_t)kc * CHUNK_E +
                                          (size_t)((w << 6) + (ct << 4) + l16) * 32 + (lg << 3));
#pragma unroll
            for (int rt = 0; rt < 2; ++rt)
#pragma unroll
                for (int ct = 0; ct < 4; ++ct)
                    acc[rt][ct] = __builtin_amdgcn_mfma_f32_16x16x32_bf16(
                        aF[rt], bF[ct], acc[rt][ct], 0, 0, 0);
        }

        // C layout: row_local = rt*16 + lg*4 + r (0..31), col = w*64 + ct*16 + l16
        if (EPI == EP_SWIGLU && m == 0) {
#pragma unroll
            for (int rt = 0; rt < 2; ++rt)
#pragma unroll
                for (int ct = 0; ct < 4; ++ct)
#pragma unroll
                    for (int r = 0; r < 4; ++r) sv[rt][ct][r] = acc[rt][ct][r];
            continue;
        }

        float v[2][4][4];
#pragma unroll
        for (int rt = 0; rt < 2; ++rt)
#pragma unroll
            for (int ct = 0; ct < 4; ++ct)
#pragma unroll
                for (int r = 0; r < 4; ++r) {
                    int row = (rt << 4) + (lg << 2) + r;
                    int col = (w << 6) + (ct << 4) + l16;
                    size_t idx = (size_t)(m0 + row) * 256 + col;
                    float x = acc[rt][ct][r];
                    if (EPI == EP_GELU_RMS) { if (bias) x += bias[col]; x = geluf(x); }
                    if (EPI == EP_RESID_RMS) x += resid[idx];
                    if (EPI == EP_SWIGLU) x *= swishf(sv[rt][ct][r]);
                    v[rt][ct][r] = x;
                }

        if (EPI == EP_GELU_RMS || EPI == EP_RESID_RMS) {
#pragma unroll
            for (int rt = 0; rt < 2; ++rt)
#pragma unroll
                for (int r = 0; r < 4; ++r) {
                    float p = 0.f;
#pragma unroll
                    for (int ct = 0; ct < 4; ++ct) p += v[rt][ct][r] * v[rt][ct][r];
                    p += __shfl_xor(p, 1, 64); p += __shfl_xor(p, 2, 64);
                    p += __shfl_xor(p, 4, 64); p += __shfl_xor(p, 8, 64);
                    int row = (rt << 4) + (lg << 2) + r;
                    if (l16 == 0) rowsum[w][row] = p;
                }
            __syncthreads();
#pragma unroll
            for (int rt = 0; rt < 2; ++rt)
#pragma unroll
                for (int r = 0; r < 4; ++r) {
                    int row = (rt << 4) + (lg << 2) + r;
                    float tot = rowsum[0][row] + rowsum[1][row] + rowsum[2][row] + rowsum[3][row];
                    float rn = rsqrtf(tot * (1.f / 256.f) + 1e-6f);
#pragma unroll
                    for (int ct = 0; ct < 4; ++ct) {
                        int col = (w << 6) + (ct << 4) + l16;
                        size_t idx = (size_t)(m0 + row) * 256 + col;
                        float o = v[rt][ct][r] * rn * lnw[col];
                        O[idx] = f2bf(o);
                        if (xout) xout[idx] = o;
                    }
                }
        } else {
#pragma unroll
            for (int rt = 0; rt < 2; ++rt)
#pragma unroll
                for (int ct = 0; ct < 4; ++ct)
#pragma unroll
                    for (int r = 0; r < 4; ++r) {
                        int row = (rt << 4) + (lg << 2) + r;
                        int col = (w << 6) + (ct << 4) + l16;
                        O[(size_t)(m0 + row) * 256 + col] = f2bf(v[rt][ct][r]);
                    }
        }
    }
}

// ---------------- retention attention: 1 barrier, fused groupnorm + swish gate ----------------
struct GArg { float l2g[8]; };

__global__ __launch_bounds__(256) void attn_k(
    const uint16_t* __restrict__ q, const uint16_t* __restrict__ kbuf,
    const uint16_t* __restrict__ vbuf, const uint16_t* __restrict__ g,
    const float* __restrict__ gns, const float* __restrict__ gnb,
    uint16_t* __restrict__ out, GArg ga)
{
    __shared__ __align__(16) uint16_t QS[256][40];
    __shared__ __align__(16) uint16_t Ks[256][40];
    __shared__ __align__(16) uint16_t Vt[32][264];
    const int b = blockIdx.x & 63, h = blockIdx.x >> 6;
    const float l2g = ga.l2g[h];
    const int t = threadIdx.x, w = t >> 6, lane = t & 63, l16 = lane & 15, lg = lane >> 4;
    const size_t base = ((size_t)b * 256) * 256 + (size_t)h * 32;

    {
        const uint4* qr = (const uint4*)(q + base + (size_t)t * 256);
        *(uint4*)&QS[t][0] = qr[0]; *(uint4*)&QS[t][8] = qr[1];
        *(uint4*)&QS[t][16] = qr[2]; *(uint4*)&QS[t][24] = qr[3];
        const uint4* kr = (const uint4*)(kbuf + base + (size_t)t * 256);
        *(uint4*)&Ks[t][0] = kr[0]; *(uint4*)&Ks[t][8] = kr[1];
        *(uint4*)&Ks[t][16] = kr[2]; *(uint4*)&Ks[t][24] = kr[3];
        union { uint4 v4[4]; uint16_t u[32]; } vv;
        const uint4* vr = (const uint4*)(vbuf + base + (size_t)t * 256);
        vv.v4[0] = vr[0]; vv.v4[1] = vr[1]; vv.v4[2] = vr[2]; vv.v4[3] = vr[3];
#pragma unroll
        for (int d = 0; d < 32; ++d) Vt[d][t] = vv.u[d];
    }
    __syncthreads();   // the only barrier

    short8 qF[4];
#pragma unroll
    for (int rt = 0; rt < 4; ++rt)
        qF[rt] = *(const short8*)&QS[(w << 6) + (rt << 4) + l16][lg << 3];

    floatx4 racc[4][2];
#pragma unroll
    for (int i = 0; i < 4; ++i) { racc[i][0] = (floatx4){0,0,0,0}; racc[i][1] = (floatx4){0,0,0,0}; }

    const float invsq = 0.17677669529663687f;
    for (int jt = 0; jt < 8; ++jt) {
        const int j0 = jt << 5;
        floatx4 sacc[4][2];
#pragma unroll
        for (int i = 0; i < 4; ++i) { sacc[i][0] = (floatx4){0,0,0,0}; sacc[i][1] = (floatx4){0,0,0,0}; }
        short8 kF[2];
#pragma unroll
        for (int ct = 0; ct < 2; ++ct)
            kF[ct] = *(const short8*)&Ks[j0 + (ct << 4) + l16][lg << 3];
#pragma unroll
        for (int rt = 0; rt < 4; ++rt)
#pragma unroll
            for (int ct = 0; ct < 2; ++ct)
                sacc[rt][ct] = __builtin_amdgcn_mfma_f32_16x16x32_bf16(
                    qF[rt], kF[ct], sacc[rt][ct], 0, 0, 0);
#pragma unroll
        for (int rt = 0; rt < 4; ++rt)
#pragma unroll
            for (int ct = 0; ct < 2; ++ct)
#pragma unroll
                for (int r = 0; r < 4; ++r) {
                    int row = (rt << 4) + (lg << 2) + r;
                    int i = (w << 6) + row;
                    int j = j0 + (ct << 4) + l16;
                    float svv = 0.f;
                    if (i >= j)
                        svv = sacc[rt][ct][r] * invsq *
                              exp2f((float)((i >> 3) - (j >> 3)) * l2g);
                    QS[(w << 6) + row][(ct << 4) + l16] = f2bf(svv);
                }
        short8 vF[2];
#pragma unroll
        for (int ct = 0; ct < 2; ++ct)
            vF[ct] = *(const short8*)&Vt[(ct << 4) + l16][j0 + (lg << 3)];
#pragma unroll
        for (int rt = 0; rt < 4; ++rt) {
            short8 sF = *(const short8*)&QS[(w << 6) + (rt << 4) + l16][lg << 3];
#pragma unroll
            for (int ct = 0; ct < 2; ++ct)
                racc[rt][ct] = __builtin_amdgcn_mfma_f32_16x16x32_bf16(
                    sF, vF[ct], racc[rt][ct], 0, 0, 0);
        }
    }

#pragma unroll
    for (int rt = 0; rt < 4; ++rt)
#pragma unroll
        for (int r = 0; r < 4; ++r) {
            float v0 = racc[rt][0][r], v1 = racc[rt][1][r];
            float s1 = v0 + v1, s2 = v0 * v0 + v1 * v1;
            s1 += __shfl_xor(s1, 1, 64); s2 += __shfl_xor(s2, 1, 64);
            s1 += __shfl_xor(s1, 2, 64); s2 += __shfl_xor(s2, 2, 64);
            s1 += __shfl_xor(s1, 4, 64); s2 += __shfl_xor(s2, 4, 64);
            s1 += __shfl_xor(s1, 8, 64); s2 += __shfl_xor(s2, 8, 64);
            float mu = s1 * (1.f / 32.f);
            float var = s2 * (1.f / 32.f) - mu * mu;
            float rstd = rsqrtf(var + 1e-5f);
            int srow = (w << 6) + (rt << 4) + (lg << 2) + r;
            size_t obase = ((size_t)b * 256 + srow) * 256 + (size_t)h * 32;
#pragma unroll
            for (int ct = 0; ct < 2; ++ct) {
                int d = (ct << 4) + l16;
                float x = ct ? v1 : v0;
                float y = (x - mu) * rstd * gns[h * 32 + d] + gnb[h * 32 + d];
                float gv = swishf(bf2f(g[obase + d]));
                out[obase + d] = f2bf(y * gv);
            }
        }
}

// ---------------- final head: out = h @ hw2 + hb2 ----------------
__global__ __launch_bounds__(256) void head_out_k(
    const uint16_t* __restrict__ h, const float* __restrict__ w2,
    const float* __restrict__ b2, float* __restrict__ out)
{
    __shared__ float hr[8][260];
    int m0 = blockIdx.x << 3;
    int t = threadIdx.x;
    {
        int r = t >> 5, c = (t & 31) << 3;
        uint4 raw = *(const uint4*)(h + (size_t)(m0 + r) * 256 + c);
        const uint16_t* us = (const uint16_t*)&raw;
#pragma unroll
        for (int j = 0; j < 8; ++j) hr[r][c + j] = bf2f(us[j]);
    }
    __syncthreads();
    int r = t >> 5, n = t & 31;
    float acc = b2[n];
#pragma unroll 4
    for (int k = 0; k < 256; ++k) acc += hr[r][k] * w2[(size_t)k * 32 + n];
    out[(size_t)(m0 + r) * 32 + n] = acc;
}

// ---------------- host ----------------
extern "C" void kernel_launch(void* const* d_in, const int* in_sizes, int n_in,
                              void* d_out, int out_size, void* d_ws, size_t ws_size,
                              hipStream_t stream)
{
    const float* action = (const float*)d_in[0];
    const float* obs    = (const float*)d_in[1];
    const float* w_enc  = (const float*)d_in[2];
    const float* ln0    = (const float*)d_in[3];
    const float* wq1 = (const float*)d_in[4];
    const float* wk1 = (const float*)d_in[5];
    const float* wv1 = (const float*)d_in[6];
    const float* wg1 = (const float*)d_in[7];
    const float* wo1 = (const float*)d_in[8];
    const float* gns1 = (const float*)d_in[9];
    const float* gnb1 = (const float*)d_in[10];
    const float* ln1  = (const float*)d_in[11];
    const float* wq2 = (const float*)d_in[12];
    const float* wk2 = (const float*)d_in[13];
    const float* wv2 = (const float*)d_in[14];
    const float* wg2 = (const float*)d_in[15];
    const float* wo2 = (const float*)d_in[16];
    const float* gns2 = (const float*)d_in[17];
    const float* gnb2 = (const float*)d_in[18];
    const float* ln2  = (const float*)d_in[19];
    const float* swgp = (const float*)d_in[20];
    const float* sw1p = (const float*)d_in[21];
    const float* sw2p = (const float*)d_in[22];
    const float* ln3  = (const float*)d_in[23];
    const float* hw1  = (const float*)d_in[24];
    const float* hb1  = (const float*)d_in[25];
    const float* hln  = (const float*)d_in[26];
    const float* hw2  = (const float*)d_in[27];
    const float* hb2  = (const float*)d_in[28];
    float* outp = (float*)d_out;

    char* ws = (char*)d_ws;
    uint16_t* wt   = (uint16_t*)(ws + 0);
    uint16_t* actb = (uint16_t*)(ws + 6291456);
    uint16_t* obsb = (uint16_t*)(ws + 7340032);
    float*    xf   = (float*)   (ws + 15728640);
    uint16_t* xb   = (uint16_t*)(ws + 32505856);
    uint16_t* bq   = (uint16_t*)(ws + 40894464);
    uint16_t* bk   = (uint16_t*)(ws + 49283072);
    uint16_t* bv   = (uint16_t*)(ws + 57671680);
    uint16_t* bg   = (uint16_t*)(ws + 66060288);
    uint16_t* brg  = (uint16_t*)(ws + 74448896);

    uint16_t* wtenc = wt;
    uint16_t* hw1t  = wt + CHUNK_E + (size_t)39 * MAT_E;
    auto WTp = [&](int ti, int s) { return wt + CHUNK_E + (size_t)(ti * 3 + s) * MAT_E; };

    GArg gaD;
    {
        const double a = log(1.0 / 32.0), bb = log(1.0 / 512.0);
        for (int hh = 0; hh < 8; ++hh) {
            double lg = a + (bb - a) * hh / 7.0;
            double gam = 1.0 - exp(lg);
            gaD.l2g[hh] = (float)(log(gam) / log(2.0));
        }
    }
    TArg ta;
    ta.src[0] = w_enc;
    ta.src[1] = wq1;  ta.src[2] = wk1;  ta.src[3] = wv1;  ta.src[4] = wg1;  ta.src[5] = wo1;
    ta.src[6] = wq2;  ta.src[7] = wk2;  ta.src[8] = wv2;  ta.src[9] = wg2;  ta.src[10] = wo2;
    ta.src[11] = swgp; ta.src[12] = sw1p; ta.src[13] = sw2p; ta.src[14] = hw1;

    tpose_k<<<dim3(4, 8, 41), 256, 0, stream>>>(ta, wt);
    cvt_k<<<512, 256, 0, stream>>>(action, actb, 131072);
    cvt_k<<<4096, 256, 0, stream>>>(obs, obsb, 1048576);

    dim3 TB(256);
    auto g1 = [&](const uint16_t* A, const uint16_t* W, uint16_t* O) {
        GemmArgs g; g.A[0] = A; g.W[0] = W; g.O[0] = O;
        g.A[1] = g.A[2] = g.A[3] = A; g.W[1] = g.W[2] = g.W[3] = W;
        g.O[1] = g.O[2] = g.O[3] = O;
        return g;
    };

    // encoder: x = rmsnorm(gelu(action @ w_enc), ln0)
    gemm5_k<EP_GELU_RMS, 32, 1><<<dim3(512, 1), TB, 0, stream>>>(
        g1(actb, wtenc, xb), nullptr, nullptr, ln0, xf);

    for (int b3 = 0; b3 < 3; ++b3) {
        {   // retention 1 (self): q,k,v,g via gridDim.y -> 2048 blocks
            GemmArgs g;
            g.A[0] = g.A[1] = g.A[2] = g.A[3] = xb;
            g.W[0] = WTp(0, b3); g.W[1] = WTp(1, b3); g.W[2] = WTp(2, b3); g.W[3] = WTp(3, b3);
            g.O[0] = bq; g.O[1] = bk; g.O[2] = bv; g.O[3] = bg;
            gemm5_k<EP_NONE, 256, 1><<<dim3(512, 4), TB, 0, stream>>>(
                g, nullptr, nullptr, nullptr, nullptr);
        }
        attn_k<<<512, TB, 0, stream>>>(bq, bk, bv, bg, gns1 + b3 * 256, gnb1 + b3 * 256, brg, gaD);
        gemm5_k<EP_RESID_RMS, 256, 1><<<dim3(512, 1), TB, 0, stream>>>(
            g1(brg, WTp(4, b3), xb), nullptr, xf, ln1 + b3 * 256, xf);
        {   // retention 2 (cross): q,g from obs_rep; k,v from x
            GemmArgs g;
            g.A[0] = obsb; g.A[1] = xb; g.A[2] = xb; g.A[3] = obsb;
            g.W[0] = WTp(5, b3); g.W[1] = WTp(6, b3); g.W[2] = WTp(7, b3); g.W[3] = WTp(8, b3);
            g.O[0] = bq; g.O[1] = bk; g.O[2] = bv; g.O[3] = bg;
            gemm5_k<EP_NONE, 256, 1><<<dim3(512, 4), TB, 0, stream>>>(
                g, nullptr, nullptr, nullptr, nullptr);
        }
        attn_k<<<512, TB, 0, stream>>>(bq, bk, bv, bg, gns2 + b3 * 256, gnb2 + b3 * 256, brg, gaD);
        gemm5_k<EP_RESID_RMS, 256, 1><<<dim3(512, 1), TB, 0, stream>>>(
            g1(brg, WTp(9, b3), xb), nullptr, obs, ln2 + b3 * 256, xf);
        {   // swiglu: gate stashed in registers (in-block NMAT=2)
            GemmArgs g;
            g.A[0] = g.A[1] = xb; g.A[2] = g.A[3] = xb;
            g.W[0] = WTp(10, b3); g.W[1] = WTp(11, b3); g.W[2] = g.W[0]; g.W[3] = g.W[1];
            g.O[0] = bk; g.O[1] = bk; g.O[2] = g.O[3] = bk;
            gemm5_k<EP_SWIGLU, 256, 2><<<dim3(512, 1), TB, 0, stream>>>(
                g, nullptr, nullptr, nullptr, nullptr);
        }
        gemm5_k<EP_RESID_RMS, 256, 1><<<dim3(512, 1), TB, 0, stream>>>(
            g1(bk, WTp(12, b3), xb), nullptr, xf, ln3 + b3 * 256, xf);
    }
    // head
    gemm5_k<EP_GELU_RMS, 256, 1><<<dim3(512, 1), TB, 0, stream>>>(
        g1(xb, hw1t, bq), hb1, nullptr, hln, nullptr);
    head_out_k<<<2048, TB, 0, stream>>>(bq, hw2, hb2, outp);
}